// Round 1
// baseline (1358.334 us; speedup 1.0000x reference)
//
#include <hip/hip_runtime.h>
#include <math.h>

#define T_TOKENS 8192
#define HID      4096
#define NEXP     512
#define TOPK     12
#define RSCALE   2.5f

#define TM   32            // tokens per block
#define BK   16            // K-chunk
#define EPAD (NEXP + 4)    // 516: Ws row pad (16B-aligned rows: 516*4 = 2064 = 16*129)
#define XPAD 36            // Xs row pad (36*4 = 144 = 16*9, keeps float4 reads aligned)

__device__ __forceinline__ unsigned int fkey(float f) {
    unsigned int u = __float_as_uint(f);
    return (u & 0x80000000u) ? ~u : (u | 0x80000000u);  // monotonic float->uint
}

__device__ __forceinline__ float pick8(const float* p, int j) {
    // j is wave-uniform; unrolled select avoids scratch spill
    float v = p[0];
    if (j == 1) v = p[1];
    if (j == 2) v = p[2];
    if (j == 3) v = p[3];
    if (j == 4) v = p[4];
    if (j == 5) v = p[5];
    if (j == 6) v = p[6];
    if (j == 7) v = p[7];
    return v;
}

__launch_bounds__(256, 1)
__global__ void router_kernel(const float* __restrict__ X,
                              const float* __restrict__ W,
                              const float* __restrict__ bias,
                              float* __restrict__ out)
{
    __shared__ float Ws[BK][EPAD];   // k-major, expert-contiguous
    __shared__ float Xs[BK][XPAD];   // k-major, token-contiguous

    const int tid  = threadIdx.x;
    const int lane = tid & 63;
    const int wave = tid >> 6;          // 0..3, owns tokens wave*8 .. wave*8+7
    const int tok0 = blockIdx.x * TM;

    float acc[8][8];
    #pragma unroll
    for (int i = 0; i < 8; i++)
        #pragma unroll
        for (int j = 0; j < 8; j++) acc[i][j] = 0.f;

    const int xt = tid >> 4;   // 0..15 token row for X staging
    const int xk = tid & 15;   // 0..15 k col

    for (int k0 = 0; k0 < HID; k0 += BK) {
        // stage X tile: 32 tokens x 16 k  (transposed into Xs[k][t])
        #pragma unroll
        for (int r = 0; r < 2; r++) {
            int t = r * 16 + xt;
            Xs[xk][t] = X[(size_t)(tok0 + t) * HID + k0 + xk];
        }
        // stage W tile: 512 experts x 16 k (transposed into Ws[k][e])
        #pragma unroll
        for (int r = 0; r < 8; r++) {
            int flat4 = r * 256 + tid;        // 0..2047 float4 slots
            int e  = flat4 >> 2;              // 4 float4 per expert row
            int kq = (flat4 & 3) * 4;
            const float4 wv = *(const float4*)&W[(size_t)e * HID + k0 + kq];
            Ws[kq + 0][e] = wv.x;
            Ws[kq + 1][e] = wv.y;
            Ws[kq + 2][e] = wv.z;
            Ws[kq + 3][e] = wv.w;
        }
        __syncthreads();

        #pragma unroll
        for (int k = 0; k < BK; k++) {
            float4 b0 = *(const float4*)&Ws[k][4 * lane];
            float4 b1 = *(const float4*)&Ws[k][256 + 4 * lane];
            float4 a0 = *(const float4*)&Xs[k][wave * 8];
            float4 a1 = *(const float4*)&Xs[k][wave * 8 + 4];
            float a[8] = {a0.x, a0.y, a0.z, a0.w, a1.x, a1.y, a1.z, a1.w};
            float b[8] = {b0.x, b0.y, b0.z, b0.w, b1.x, b1.y, b1.z, b1.w};
            #pragma unroll
            for (int i = 0; i < 8; i++)
                #pragma unroll
                for (int j = 0; j < 8; j++)
                    acc[i][j] = fmaf(a[i], b[j], acc[i][j]);
        }
        __syncthreads();
    }

    // ---- epilogue: per-token softmax + biased top-12, wave-internal ----
    // lane's experts: j<4 -> 4*lane+j ; j>=4 -> 256+4*lane+(j-4)
    const float4 bs0 = *(const float4*)&bias[4 * lane];
    const float4 bs1 = *(const float4*)&bias[256 + 4 * lane];
    const float br[8] = {bs0.x, bs0.y, bs0.z, bs0.w, bs1.x, bs1.y, bs1.z, bs1.w};

    for (int i = 0; i < 8; i++) {
        const int tok = tok0 + wave * 8 + i;

        // wave max
        float m = acc[i][0];
        #pragma unroll
        for (int j = 1; j < 8; j++) m = fmaxf(m, acc[i][j]);
        #pragma unroll
        for (int off = 32; off >= 1; off >>= 1) m = fmaxf(m, __shfl_xor(m, off));

        // exp + wave sum
        float p[8];
        float s = 0.f;
        #pragma unroll
        for (int j = 0; j < 8; j++) { p[j] = expf(acc[i][j] - m); s += p[j]; }
        #pragma unroll
        for (int off = 32; off >= 1; off >>= 1) s += __shfl_xor(s, off);
        const float inv = 1.f / s;

        float pb[8], bb[8];
        #pragma unroll
        for (int j = 0; j < 8; j++) {
            pb[j] = p[j] * inv;            // unbiased prob (softmax)
            bb[j] = pb[j] + br[j];         // biased score for selection
        }

        // top-12 by biased score, desc; ties -> smaller expert index
        for (int kk = 0; kk < TOPK; kk++) {
            unsigned long long key = 0ull;
            #pragma unroll
            for (int j = 0; j < 8; j++) {
                int e = (j < 4) ? (4 * lane + j) : (256 + 4 * lane + (j - 4));
                unsigned long long k64 =
                    ((unsigned long long)fkey(bb[j]) << 32) |
                    (unsigned long long)(unsigned int)(1023 - e);
                key = (k64 > key) ? k64 : key;
            }
            #pragma unroll
            for (int off = 32; off >= 1; off >>= 1) {
                unsigned long long o = __shfl_xor(key, off);
                key = (o > key) ? o : key;
            }
            const int estar = 1023 - (int)(unsigned int)(key & 0xffffffffull);

            int lstar, jstar;
            if (estar < 256) { lstar = estar >> 2;         jstar = estar & 3; }
            else             { lstar = (estar - 256) >> 2; jstar = 4 + ((estar - 256) & 3); }

            const float pj   = pick8(pb, jstar);     // jstar is wave-uniform
            const float psel = __shfl(pj, lstar);

            if (lane == lstar) {
                if (jstar == 0) bb[0] = -INFINITY;
                if (jstar == 1) bb[1] = -INFINITY;
                if (jstar == 2) bb[2] = -INFINITY;
                if (jstar == 3) bb[3] = -INFINITY;
                if (jstar == 4) bb[4] = -INFINITY;
                if (jstar == 5) bb[5] = -INFINITY;
                if (jstar == 6) bb[6] = -INFINITY;
                if (jstar == 7) bb[7] = -INFINITY;
            }

            if (lane == 0) {
                out[(size_t)tok * TOPK + kk] = psel * RSCALE;
                out[(size_t)T_TOKENS * TOPK + (size_t)tok * TOPK + kk] = (float)estar;
            }
        }
    }
}

extern "C" void kernel_launch(void* const* d_in, const int* in_sizes, int n_in,
                              void* d_out, int out_size, void* d_ws, size_t ws_size,
                              hipStream_t stream)
{
    const float* X    = (const float*)d_in[0];   // [8192, 4096]
    const float* W    = (const float*)d_in[1];   // [512, 4096]
    const float* bias = (const float*)d_in[2];   // [512]
    float* out = (float*)d_out;                  // [8192*12 weights][8192*12 indices-as-float]

    router_kernel<<<dim3(T_TOKENS / TM), dim3(256), 0, stream>>>(X, W, bias, out);
}

// Round 3
// 425.781 us; speedup vs baseline: 3.1902x; 3.1902x over previous
//
#include <hip/hip_runtime.h>
#include <math.h>

#define T_TOKENS 8192
#define HID      4096
#define NEXP     512
#define TOPK     12
#define RSCALE   2.5f

// ---------------- shared helpers (verified round 1) ----------------

__device__ __forceinline__ unsigned int fkey(float f) {
    unsigned int u = __float_as_uint(f);
    return (u & 0x80000000u) ? ~u : (u | 0x80000000u);  // monotonic float->uint
}

__device__ __forceinline__ float pick8(const float* p, int j) {
    float v = p[0];
    if (j == 1) v = p[1];
    if (j == 2) v = p[2];
    if (j == 3) v = p[3];
    if (j == 4) v = p[4];
    if (j == 5) v = p[5];
    if (j == 6) v = p[6];
    if (j == 7) v = p[7];
    return v;
}

// ================== Kernel 1: fp16x3 split-precision MFMA GEMM ==================
// x = xh + 2^-12 xl + O(2^-22 x)   (RNE hi, RNE scaled residual)
// logits*64 = accH(xh*wh) + 2^-12 * accC(xh*wl + xl*wh)   with wh/wl planes of 64*W.

typedef __attribute__((ext_vector_type(8))) _Float16 f16x8;
typedef __attribute__((ext_vector_type(4))) float    f32x4;

#define BM   128
#define BN   128
#define BKF  32          // fp32 k per iteration
#define ROWB 144         // LDS row: 64 B hi plane | 16 B pad | 64 B lo plane

// float4 -> 4 packed hi halves (uint2) + 4 packed scaled-lo halves (uint2), RNE
__device__ __forceinline__ void cvt4(const float4 f, uint2& h, uint2& l) {
    _Float16 h0 = (_Float16)f.x, h1 = (_Float16)f.y;
    _Float16 h2 = (_Float16)f.z, h3 = (_Float16)f.w;
    float r0 = (f.x - (float)h0) * 4096.f;
    float r1 = (f.y - (float)h1) * 4096.f;
    float r2 = (f.z - (float)h2) * 4096.f;
    float r3 = (f.w - (float)h3) * 4096.f;
    _Float16 l0 = (_Float16)r0, l1 = (_Float16)r1;
    _Float16 l2 = (_Float16)r2, l3 = (_Float16)r3;
    union P { _Float16 q[2]; unsigned int u; } p;
    p.q[0] = h0; p.q[1] = h1; h.x = p.u;
    p.q[0] = h2; p.q[1] = h3; h.y = p.u;
    p.q[0] = l0; p.q[1] = l1; l.x = p.u;
    p.q[0] = l2; p.q[1] = l3; l.y = p.u;
}

__launch_bounds__(256, 1)
__global__ void gemm_kernel(const float* __restrict__ X,
                            const float* __restrict__ W,
                            float* __restrict__ logits)
{
    __shared__ __align__(16) unsigned char Xs[BM * ROWB];   // 18 KB
    __shared__ __align__(16) unsigned char Ws[BN * ROWB];   // 18 KB

    const int tid  = threadIdx.x;
    const int lane = tid & 63;
    const int wave = tid >> 6;

    const int n_grp = blockIdx.x & 3;
    const int m_grp = blockIdx.x >> 2;
    const int tok0  = m_grp * BM;
    const int e0    = n_grp * BN;

    const int waveM = (wave >> 1) * 64;
    const int waveN = (wave & 1) * 64;
    const int m16   = lane & 15;
    const int q     = lane >> 4;

    const float* Xb = X + (size_t)tok0 * HID;
    const float* Wb = W + (size_t)e0 * HID;

    // ---- software-pipelined staging: prefetch tile k0=0 into regs ----
    float4 px[4], pw[4];
    #pragma unroll
    for (int s = 0; s < 4; s++) {
        const int flat = s * 256 + tid;
        const int row = flat >> 3, grp = flat & 7;
        px[s] = *(const float4*)&Xb[(size_t)row * HID + grp * 4];
        pw[s] = *(const float4*)&Wb[(size_t)row * HID + grp * 4];
    }

    f32x4 accH[4][4], accC[4][4];
    #pragma unroll
    for (int mi = 0; mi < 4; mi++)
        #pragma unroll
        for (int ni = 0; ni < 4; ni++) { accH[mi][ni] = (f32x4)0.f; accC[mi][ni] = (f32x4)0.f; }

    #pragma unroll 1
    for (int k0 = 0; k0 < HID; k0 += BKF) {
        // convert prefetched tile -> LDS planes
        #pragma unroll
        for (int s = 0; s < 4; s++) {
            const int flat = s * 256 + tid;
            const int row = flat >> 3, grp = flat & 7;
            uint2 h, l;
            cvt4(px[s], h, l);
            *(uint2*)(Xs + row * ROWB + grp * 8)      = h;
            *(uint2*)(Xs + row * ROWB + 80 + grp * 8) = l;
            const float4 w64 = make_float4(pw[s].x * 64.f, pw[s].y * 64.f,
                                           pw[s].z * 64.f, pw[s].w * 64.f);
            cvt4(w64, h, l);
            *(uint2*)(Ws + row * ROWB + grp * 8)      = h;
            *(uint2*)(Ws + row * ROWB + 80 + grp * 8) = l;
        }
        __syncthreads();

        // prefetch next tile (overlaps MFMA phase below)
        if (k0 + BKF < HID) {
            #pragma unroll
            for (int s = 0; s < 4; s++) {
                const int flat = s * 256 + tid;
                const int row = flat >> 3, grp = flat & 7;
                px[s] = *(const float4*)&Xb[(size_t)row * HID + (k0 + BKF) + grp * 4];
                pw[s] = *(const float4*)&Wb[(size_t)row * HID + (k0 + BKF) + grp * 4];
            }
        }

        // fragments: A[m=lane&15][k=q*8+j], B[n=lane&15][k=q*8+j]
        f16x8 Ah[4], Al[4], Bh[4], Bl[4];
        #pragma unroll
        for (int mi = 0; mi < 4; mi++) {
            const unsigned char* p = Xs + (waveM + mi * 16 + m16) * ROWB + q * 16;
            Ah[mi] = *(const f16x8*)p;
            Al[mi] = *(const f16x8*)(p + 80);
        }
        #pragma unroll
        for (int ni = 0; ni < 4; ni++) {
            const unsigned char* p = Ws + (waveN + ni * 16 + m16) * ROWB + q * 16;
            Bh[ni] = *(const f16x8*)p;
            Bl[ni] = *(const f16x8*)(p + 80);
        }

        #pragma unroll
        for (int mi = 0; mi < 4; mi++)
            #pragma unroll
            for (int ni = 0; ni < 4; ni++) {
                accH[mi][ni] = __builtin_amdgcn_mfma_f32_16x16x32_f16(Ah[mi], Bh[ni], accH[mi][ni], 0, 0, 0);
                accC[mi][ni] = __builtin_amdgcn_mfma_f32_16x16x32_f16(Ah[mi], Bl[ni], accC[mi][ni], 0, 0, 0);
                accC[mi][ni] = __builtin_amdgcn_mfma_f32_16x16x32_f16(Al[mi], Bh[ni], accC[mi][ni], 0, 0, 0);
            }
        __syncthreads();
    }

    // C/D layout (verified m89/m91): col = lane&15, row = q*4 + reg
    #pragma unroll
    for (int mi = 0; mi < 4; mi++)
        #pragma unroll
        for (int ni = 0; ni < 4; ni++) {
            const int e = e0 + waveN + ni * 16 + m16;
            #pragma unroll
            for (int r = 0; r < 4; r++) {
                const int token = tok0 + waveM + mi * 16 + q * 4 + r;
                logits[(size_t)token * NEXP + e] =
                    (accH[mi][ni][r] + accC[mi][ni][r] * (1.f / 4096.f)) * (1.f / 64.f);
            }
        }
}

// ================== Kernel 2: softmax + biased top-12 (round-1 verified) ==================

__launch_bounds__(256, 1)
__global__ void topk_kernel(const float* __restrict__ logits,
                            const float* __restrict__ bias,
                            float* __restrict__ out)
{
    const int tid  = threadIdx.x;
    const int lane = tid & 63;
    const int wave = tid >> 6;
    const int tokBase = blockIdx.x * 32 + wave * 8;

    const float4 bs0 = *(const float4*)&bias[4 * lane];
    const float4 bs1 = *(const float4*)&bias[256 + 4 * lane];
    const float br[8] = {bs0.x, bs0.y, bs0.z, bs0.w, bs1.x, bs1.y, bs1.z, bs1.w};

    for (int i = 0; i < 8; i++) {
        const int tok = tokBase + i;
        const float4 z0 = *(const float4*)&logits[(size_t)tok * NEXP + 4 * lane];
        const float4 z1 = *(const float4*)&logits[(size_t)tok * NEXP + 256 + 4 * lane];
        float z[8] = {z0.x, z0.y, z0.z, z0.w, z1.x, z1.y, z1.z, z1.w};

        float m = z[0];
        #pragma unroll
        for (int j = 1; j < 8; j++) m = fmaxf(m, z[j]);
        #pragma unroll
        for (int off = 32; off >= 1; off >>= 1) m = fmaxf(m, __shfl_xor(m, off));

        float p[8];
        float s = 0.f;
        #pragma unroll
        for (int j = 0; j < 8; j++) { p[j] = expf(z[j] - m); s += p[j]; }
        #pragma unroll
        for (int off = 32; off >= 1; off >>= 1) s += __shfl_xor(s, off);
        const float inv = 1.f / s;

        float pb[8], bb[8];
        #pragma unroll
        for (int j = 0; j < 8; j++) {
            pb[j] = p[j] * inv;
            bb[j] = pb[j] + br[j];
        }

        for (int kk = 0; kk < TOPK; kk++) {
            unsigned long long key = 0ull;
            #pragma unroll
            for (int j = 0; j < 8; j++) {
                int e = (j < 4) ? (4 * lane + j) : (256 + 4 * lane + (j - 4));
                unsigned long long k64 =
                    ((unsigned long long)fkey(bb[j]) << 32) |
                    (unsigned long long)(unsigned int)(1023 - e);
                key = (k64 > key) ? k64 : key;
            }
            #pragma unroll
            for (int off = 32; off >= 1; off >>= 1) {
                unsigned long long o = __shfl_xor(key, off);
                key = (o > key) ? o : key;
            }
            const int estar = 1023 - (int)(unsigned int)(key & 0xffffffffull);

            int lstar, jstar;
            if (estar < 256) { lstar = estar >> 2;         jstar = estar & 3; }
            else             { lstar = (estar - 256) >> 2; jstar = 4 + ((estar - 256) & 3); }

            const float pj   = pick8(pb, jstar);
            const float psel = __shfl(pj, lstar);

            if (lane == lstar) {
                if (jstar == 0) bb[0] = -INFINITY;
                if (jstar == 1) bb[1] = -INFINITY;
                if (jstar == 2) bb[2] = -INFINITY;
                if (jstar == 3) bb[3] = -INFINITY;
                if (jstar == 4) bb[4] = -INFINITY;
                if (jstar == 5) bb[5] = -INFINITY;
                if (jstar == 6) bb[6] = -INFINITY;
                if (jstar == 7) bb[7] = -INFINITY;
            }

            if (lane == 0) {
                out[(size_t)tok * TOPK + kk] = psel * RSCALE;
                out[(size_t)T_TOKENS * TOPK + (size_t)tok * TOPK + kk] = (float)estar;
            }
        }
    }
}

// ================== Fallback: round-1 fused fp32 kernel (verified) ==================

#define TM   32
#define BK   16
#define EPAD (NEXP + 4)
#define XPAD 36

__launch_bounds__(256, 1)
__global__ void router_kernel(const float* __restrict__ X,
                              const float* __restrict__ W,
                              const float* __restrict__ bias,
                              float* __restrict__ out)
{
    __shared__ float Wsh[BK][EPAD];
    __shared__ float Xsh[BK][XPAD];

    const int tid  = threadIdx.x;
    const int lane = tid & 63;
    const int wave = tid >> 6;
    const int tok0 = blockIdx.x * TM;

    float acc[8][8];
    #pragma unroll
    for (int i = 0; i < 8; i++)
        #pragma unroll
        for (int j = 0; j < 8; j++) acc[i][j] = 0.f;

    const int xt = tid >> 4;
    const int xk = tid & 15;

    for (int k0 = 0; k0 < HID; k0 += BK) {
        #pragma unroll
        for (int r = 0; r < 2; r++) {
            int t = r * 16 + xt;
            Xsh[xk][t] = X[(size_t)(tok0 + t) * HID + k0 + xk];
        }
        #pragma unroll
        for (int r = 0; r < 8; r++) {
            int flat4 = r * 256 + tid;
            int e  = flat4 >> 2;
            int kq = (flat4 & 3) * 4;
            const float4 wv = *(const float4*)&W[(size_t)e * HID + k0 + kq];
            Wsh[kq + 0][e] = wv.x;
            Wsh[kq + 1][e] = wv.y;
            Wsh[kq + 2][e] = wv.z;
            Wsh[kq + 3][e] = wv.w;
        }
        __syncthreads();

        #pragma unroll
        for (int k = 0; k < BK; k++) {
            float4 b0 = *(const float4*)&Wsh[k][4 * lane];
            float4 b1 = *(const float4*)&Wsh[k][256 + 4 * lane];
            float4 a0 = *(const float4*)&Xsh[k][wave * 8];
            float4 a1 = *(const float4*)&Xsh[k][wave * 8 + 4];
            float a[8] = {a0.x, a0.y, a0.z, a0.w, a1.x, a1.y, a1.z, a1.w};
            float b[8] = {b0.x, b0.y, b0.z, b0.w, b1.x, b1.y, b1.z, b1.w};
            #pragma unroll
            for (int i = 0; i < 8; i++)
                #pragma unroll
                for (int j = 0; j < 8; j++)
                    acc[i][j] = fmaf(a[i], b[j], acc[i][j]);
        }
        __syncthreads();
    }

    const float4 bs0 = *(const float4*)&bias[4 * lane];
    const float4 bs1 = *(const float4*)&bias[256 + 4 * lane];
    const float br[8] = {bs0.x, bs0.y, bs0.z, bs0.w, bs1.x, bs1.y, bs1.z, bs1.w};

    for (int i = 0; i < 8; i++) {
        const int tok = tok0 + wave * 8 + i;

        float m = acc[i][0];
        #pragma unroll
        for (int j = 1; j < 8; j++) m = fmaxf(m, acc[i][j]);
        #pragma unroll
        for (int off = 32; off >= 1; off >>= 1) m = fmaxf(m, __shfl_xor(m, off));

        float p[8];
        float s = 0.f;
        #pragma unroll
        for (int j = 0; j < 8; j++) { p[j] = expf(acc[i][j] - m); s += p[j]; }
        #pragma unroll
        for (int off = 32; off >= 1; off >>= 1) s += __shfl_xor(s, off);
        const float inv = 1.f / s;

        float pb[8], bb[8];
        #pragma unroll
        for (int j = 0; j < 8; j++) {
            pb[j] = p[j] * inv;
            bb[j] = pb[j] + br[j];
        }

        for (int kk = 0; kk < TOPK; kk++) {
            unsigned long long key = 0ull;
            #pragma unroll
            for (int j = 0; j < 8; j++) {
                int e = (j < 4) ? (4 * lane + j) : (256 + 4 * lane + (j - 4));
                unsigned long long k64 =
                    ((unsigned long long)fkey(bb[j]) << 32) |
                    (unsigned long long)(unsigned int)(1023 - e);
                key = (k64 > key) ? k64 : key;
            }
            #pragma unroll
            for (int off = 32; off >= 1; off >>= 1) {
                unsigned long long o = __shfl_xor(key, off);
                key = (o > key) ? o : key;
            }
            const int estar = 1023 - (int)(unsigned int)(key & 0xffffffffull);

            int lstar, jstar;
            if (estar < 256) { lstar = estar >> 2;         jstar = estar & 3; }
            else             { lstar = (estar - 256) >> 2; jstar = 4 + ((estar - 256) & 3); }

            const float pj   = pick8(pb, jstar);
            const float psel = __shfl(pj, lstar);

            if (lane == lstar) {
                if (jstar == 0) bb[0] = -INFINITY;
                if (jstar == 1) bb[1] = -INFINITY;
                if (jstar == 2) bb[2] = -INFINITY;
                if (jstar == 3) bb[3] = -INFINITY;
                if (jstar == 4) bb[4] = -INFINITY;
                if (jstar == 5) bb[5] = -INFINITY;
                if (jstar == 6) bb[6] = -INFINITY;
                if (jstar == 7) bb[7] = -INFINITY;
            }

            if (lane == 0) {
                out[(size_t)tok * TOPK + kk] = psel * RSCALE;
                out[(size_t)T_TOKENS * TOPK + (size_t)tok * TOPK + kk] = (float)estar;
            }
        }
    }
}

// ================== launcher ==================

extern "C" void kernel_launch(void* const* d_in, const int* in_sizes, int n_in,
                              void* d_out, int out_size, void* d_ws, size_t ws_size,
                              hipStream_t stream)
{
    const float* X    = (const float*)d_in[0];   // [8192, 4096]
    const float* W    = (const float*)d_in[1];   // [512, 4096]
    const float* bias = (const float*)d_in[2];   // [512]
    float* out = (float*)d_out;

    const size_t need = (size_t)T_TOKENS * NEXP * sizeof(float);  // 16 MB logits
    if (ws_size >= need) {
        float* logits = (float*)d_ws;
        gemm_kernel<<<dim3(256), dim3(256), 0, stream>>>(X, W, logits);
        topk_kernel<<<dim3(256), dim3(256), 0, stream>>>(logits, bias, out);
    } else {
        router_kernel<<<dim3(T_TOKENS / TM), dim3(256), 0, stream>>>(X, W, bias, out);
    }
}

// Round 4
// 366.722 us; speedup vs baseline: 3.7040x; 1.1610x over previous
//
#include <hip/hip_runtime.h>
#include <math.h>

#define T_TOKENS 8192
#define HID      4096
#define NEXP     512
#define TOPK     12
#define RSCALE   2.5f

// ---------------- shared helpers (verified round 1) ----------------

__device__ __forceinline__ unsigned int fkey(float f) {
    unsigned int u = __float_as_uint(f);
    return (u & 0x80000000u) ? ~u : (u | 0x80000000u);  // monotonic float->uint
}

__device__ __forceinline__ float pick8(const float* p, int j) {
    float v = p[0];
    if (j == 1) v = p[1];
    if (j == 2) v = p[2];
    if (j == 3) v = p[3];
    if (j == 4) v = p[4];
    if (j == 5) v = p[5];
    if (j == 6) v = p[6];
    if (j == 7) v = p[7];
    return v;
}

// ================== fp16x3 split-precision common ==================
// x = xh + 2^-12 xl + O(2^-22 x)   (RNE hi, RNE scaled residual)
// logits*64 = accH(xh*wh) + 2^-12 * accC(xh*wl + xl*wh), W pre-scaled *64.

typedef __attribute__((ext_vector_type(8))) _Float16 f16x8;
typedef __attribute__((ext_vector_type(4))) float    f32x4;

#define BM   128
#define BN   128
#define BKF  32          // fp32 k per iteration
#define ROWB 144         // padded X LDS row: 64 B hi | 16 B pad | 64 B lo

// float4 -> 4 packed hi halves (uint2) + 4 packed scaled-lo halves (uint2), RNE
__device__ __forceinline__ void cvt4(const float4 f, uint2& h, uint2& l) {
    _Float16 h0 = (_Float16)f.x, h1 = (_Float16)f.y;
    _Float16 h2 = (_Float16)f.z, h3 = (_Float16)f.w;
    float r0 = (f.x - (float)h0) * 4096.f;
    float r1 = (f.y - (float)h1) * 4096.f;
    float r2 = (f.z - (float)h2) * 4096.f;
    float r3 = (f.w - (float)h3) * 4096.f;
    _Float16 l0 = (_Float16)r0, l1 = (_Float16)r1;
    _Float16 l2 = (_Float16)r2, l3 = (_Float16)r3;
    union P { _Float16 q[2]; unsigned int u; } p;
    p.q[0] = h0; p.q[1] = h1; h.x = p.u;
    p.q[0] = h2; p.q[1] = h3; h.y = p.u;
    p.q[0] = l0; p.q[1] = l1; l.x = p.u;
    p.q[0] = l2; p.q[1] = l3; l.y = p.u;
}

__device__ __forceinline__ void load_lds16(const void* g, void* l) {
    __builtin_amdgcn_global_load_lds((const __attribute__((address_space(1))) void*)g,
                                     (__attribute__((address_space(3))) void*)l,
                                     16, 0, 0);
}

// ================== Kernel 0: W -> fp16 planes, DMA-ready swizzled layout ==================
// Wp slot (kc, e, p) 16 B at ((kc*512+e)*8+p)*16 holds group g = p ^ (e&7):
//   g<4: hi fp16 of 64*W[e][kc*32+g*8 .. +7];  g>=4: lo plane of same k-range.
// Bitwise identical to cvt4's planes (same RNE formulas).

__global__ void wconv_kernel(const float* __restrict__ W, uint4* __restrict__ Wp) {
    const int gid = blockIdx.x * 256 + threadIdx.x;   // 524288 total
    const int e  = gid >> 10;
    const int kc = (gid >> 3) & 127;
    const int p  = gid & 7;
    const int g  = p ^ (e & 7);
    const int kbase = kc * 32 + (g & 3) * 8;
    const float* src = W + (size_t)e * HID + kbase;
    const float4 f0 = *(const float4*)src;
    const float4 f1 = *(const float4*)(src + 4);
    const float v[8] = {f0.x, f0.y, f0.z, f0.w, f1.x, f1.y, f1.z, f1.w};

    union H { _Float16 f; unsigned short u; } cv;
    unsigned short h[8];
    if (g < 4) {
        #pragma unroll
        for (int j = 0; j < 8; j++) { cv.f = (_Float16)(v[j] * 64.f); h[j] = cv.u; }
    } else {
        #pragma unroll
        for (int j = 0; j < 8; j++) {
            const float w64 = v[j] * 64.f;
            const _Float16 hh = (_Float16)w64;
            cv.f = (_Float16)((w64 - (float)hh) * 4096.f);
            h[j] = cv.u;
        }
    }
    union O { unsigned short q[8]; uint4 u; } o;
    #pragma unroll
    for (int j = 0; j < 8; j++) o.q[j] = h[j];
    Wp[(size_t)(kc * 512 + e) * 8 + p] = o.u;
}

// ================== Kernel 1: GEMM, X converted in-kernel, W planes DMA'd ==================

__launch_bounds__(256, 1)
__global__ void gemm2_kernel(const float* __restrict__ X,
                             const uint4* __restrict__ Wp,
                             float* __restrict__ logits)
{
    __shared__ __align__(16) unsigned char Xs[BM * ROWB];    // 18 KB, padded rows
    __shared__ __align__(16) unsigned char Ws[BN * 128];     // 16 KB, swizzled rows

    const int tid  = threadIdx.x;
    const int lane = tid & 63;
    const int wave = tid >> 6;

    // XCD-aware swizzle: XCD x (= blockIdx%8) owns m_groups x*8..x*8+7, all 4 n_groups
    // co-resident on the same XCD -> X tile hits its L2 once.
    const int x8    = blockIdx.x & 7;
    const int i32   = blockIdx.x >> 3;        // 0..31
    const int m_grp = x8 * 8 + (i32 >> 2);    // 0..63
    const int n_grp = i32 & 3;
    const int tok0  = m_grp * BM;
    const int e0    = n_grp * BN;

    const int waveM = (wave >> 1) * 64;
    const int waveN = (wave & 1) * 64;
    const int m16   = lane & 15;
    const int q     = lane >> 4;

    const float* Xb = X + (size_t)tok0 * HID;

    // W DMA addressing: per-lane global src, wave-uniform LDS dst; both advance
    // 1024 B per 8-row segment. Content is pre-swizzled by wconv.
    const char* wsrc = (const char*)Wp + (size_t)(e0 + wave * 32) * 128 + lane * 16;
    unsigned char* wdst = Ws + (wave * 32) * 128;

    // ---- prefetch X tile kc=0 into regs ----
    float4 px[4];
    #pragma unroll
    for (int s = 0; s < 4; s++) {
        const int flat = s * 256 + tid;
        const int row = flat >> 3, grp = flat & 7;
        px[s] = *(const float4*)&Xb[(size_t)row * HID + grp * 4];
    }

    f32x4 accH[4][4], accC[4][4];
    #pragma unroll
    for (int mi = 0; mi < 4; mi++)
        #pragma unroll
        for (int ni = 0; ni < 4; ni++) { accH[mi][ni] = (f32x4)0.f; accC[mi][ni] = (f32x4)0.f; }

    #pragma unroll 1
    for (int kc = 0; kc < HID / BKF; kc++) {
        __syncthreads();   // prior iteration done reading LDS

        // async W planes -> LDS (issued first: max overlap with X conversion)
        #pragma unroll
        for (int s = 0; s < 4; s++)
            load_lds16(wsrc + (size_t)kc * (512 * 128) + s * 1024, wdst + s * 1024);

        // X: convert prefetched tile -> padded LDS planes
        #pragma unroll
        for (int s = 0; s < 4; s++) {
            const int flat = s * 256 + tid;
            const int row = flat >> 3, grp = flat & 7;
            uint2 h, l;
            cvt4(px[s], h, l);
            *(uint2*)(Xs + row * ROWB + grp * 8)      = h;
            *(uint2*)(Xs + row * ROWB + 80 + grp * 8) = l;
        }
        __syncthreads();   // drains vmcnt (W DMA) + LDS writes

        // prefetch next X tile (overlaps MFMA phase)
        if (kc + 1 < HID / BKF) {
            #pragma unroll
            for (int s = 0; s < 4; s++) {
                const int flat = s * 256 + tid;
                const int row = flat >> 3, grp = flat & 7;
                px[s] = *(const float4*)&Xb[(size_t)row * HID + (kc + 1) * BKF + grp * 4];
            }
        }

        // fragments: A[m=lane&15][k=q*8+j], B[n=lane&15][k=q*8+j]
        f16x8 Ah[4], Al[4], Bh[4], Bl[4];
        #pragma unroll
        for (int mi = 0; mi < 4; mi++) {
            const unsigned char* p = Xs + (waveM + mi * 16 + m16) * ROWB + q * 16;
            Ah[mi] = *(const f16x8*)p;
            Al[mi] = *(const f16x8*)(p + 80);
        }
        #pragma unroll
        for (int ni = 0; ni < 4; ni++) {
            const int row = waveN + ni * 16 + m16;
            const unsigned char* pr = Ws + row * 128;
            const int r7 = row & 7;
            Bh[ni] = *(const f16x8*)(pr + ((q ^ r7) * 16));
            Bl[ni] = *(const f16x8*)(pr + (((4 | q) ^ r7) * 16));
        }

        #pragma unroll
        for (int mi = 0; mi < 4; mi++)
            #pragma unroll
            for (int ni = 0; ni < 4; ni++) {
                accH[mi][ni] = __builtin_amdgcn_mfma_f32_16x16x32_f16(Ah[mi], Bh[ni], accH[mi][ni], 0, 0, 0);
                accC[mi][ni] = __builtin_amdgcn_mfma_f32_16x16x32_f16(Ah[mi], Bl[ni], accC[mi][ni], 0, 0, 0);
                accC[mi][ni] = __builtin_amdgcn_mfma_f32_16x16x32_f16(Al[mi], Bh[ni], accC[mi][ni], 0, 0, 0);
            }
    }

    // C/D layout (verified m89/m91): col = lane&15, row = q*4 + reg
    #pragma unroll
    for (int mi = 0; mi < 4; mi++)
        #pragma unroll
        for (int ni = 0; ni < 4; ni++) {
            const int e = e0 + waveN + ni * 16 + m16;
            #pragma unroll
            for (int r = 0; r < 4; r++) {
                const int token = tok0 + waveM + mi * 16 + q * 4 + r;
                logits[(size_t)token * NEXP + e] =
                    (accH[mi][ni][r] + accC[mi][ni][r] * (1.f / 4096.f)) * (1.f / 64.f);
            }
        }
}

// ================== Fallback GEMM (round-3, verified): X+W converted in-kernel ==================

__launch_bounds__(256, 1)
__global__ void gemm_kernel(const float* __restrict__ X,
                            const float* __restrict__ W,
                            float* __restrict__ logits)
{
    __shared__ __align__(16) unsigned char Xs[BM * ROWB];
    __shared__ __align__(16) unsigned char Ws[BN * ROWB];

    const int tid  = threadIdx.x;
    const int lane = tid & 63;
    const int wave = tid >> 6;

    const int n_grp = blockIdx.x & 3;
    const int m_grp = blockIdx.x >> 2;
    const int tok0  = m_grp * BM;
    const int e0    = n_grp * BN;

    const int waveM = (wave >> 1) * 64;
    const int waveN = (wave & 1) * 64;
    const int m16   = lane & 15;
    const int q     = lane >> 4;

    const float* Xb = X + (size_t)tok0 * HID;
    const float* Wb = W + (size_t)e0 * HID;

    float4 px[4], pw[4];
    #pragma unroll
    for (int s = 0; s < 4; s++) {
        const int flat = s * 256 + tid;
        const int row = flat >> 3, grp = flat & 7;
        px[s] = *(const float4*)&Xb[(size_t)row * HID + grp * 4];
        pw[s] = *(const float4*)&Wb[(size_t)row * HID + grp * 4];
    }

    f32x4 accH[4][4], accC[4][4];
    #pragma unroll
    for (int mi = 0; mi < 4; mi++)
        #pragma unroll
        for (int ni = 0; ni < 4; ni++) { accH[mi][ni] = (f32x4)0.f; accC[mi][ni] = (f32x4)0.f; }

    #pragma unroll 1
    for (int k0 = 0; k0 < HID; k0 += BKF) {
        #pragma unroll
        for (int s = 0; s < 4; s++) {
            const int flat = s * 256 + tid;
            const int row = flat >> 3, grp = flat & 7;
            uint2 h, l;
            cvt4(px[s], h, l);
            *(uint2*)(Xs + row * ROWB + grp * 8)      = h;
            *(uint2*)(Xs + row * ROWB + 80 + grp * 8) = l;
            const float4 w64 = make_float4(pw[s].x * 64.f, pw[s].y * 64.f,
                                           pw[s].z * 64.f, pw[s].w * 64.f);
            cvt4(w64, h, l);
            *(uint2*)(Ws + row * ROWB + grp * 8)      = h;
            *(uint2*)(Ws + row * ROWB + 80 + grp * 8) = l;
        }
        __syncthreads();

        if (k0 + BKF < HID) {
            #pragma unroll
            for (int s = 0; s < 4; s++) {
                const int flat = s * 256 + tid;
                const int row = flat >> 3, grp = flat & 7;
                px[s] = *(const float4*)&Xb[(size_t)row * HID + (k0 + BKF) + grp * 4];
                pw[s] = *(const float4*)&Wb[(size_t)row * HID + (k0 + BKF) + grp * 4];
            }
        }

        f16x8 Ah[4], Al[4], Bh[4], Bl[4];
        #pragma unroll
        for (int mi = 0; mi < 4; mi++) {
            const unsigned char* p = Xs + (waveM + mi * 16 + m16) * ROWB + q * 16;
            Ah[mi] = *(const f16x8*)p;
            Al[mi] = *(const f16x8*)(p + 80);
        }
        #pragma unroll
        for (int ni = 0; ni < 4; ni++) {
            const unsigned char* p = Ws + (waveN + ni * 16 + m16) * ROWB + q * 16;
            Bh[ni] = *(const f16x8*)p;
            Bl[ni] = *(const f16x8*)(p + 80);
        }

        #pragma unroll
        for (int mi = 0; mi < 4; mi++)
            #pragma unroll
            for (int ni = 0; ni < 4; ni++) {
                accH[mi][ni] = __builtin_amdgcn_mfma_f32_16x16x32_f16(Ah[mi], Bh[ni], accH[mi][ni], 0, 0, 0);
                accC[mi][ni] = __builtin_amdgcn_mfma_f32_16x16x32_f16(Ah[mi], Bl[ni], accC[mi][ni], 0, 0, 0);
                accC[mi][ni] = __builtin_amdgcn_mfma_f32_16x16x32_f16(Al[mi], Bh[ni], accC[mi][ni], 0, 0, 0);
            }
        __syncthreads();
    }

    #pragma unroll
    for (int mi = 0; mi < 4; mi++)
        #pragma unroll
        for (int ni = 0; ni < 4; ni++) {
            const int e = e0 + waveN + ni * 16 + m16;
            #pragma unroll
            for (int r = 0; r < 4; r++) {
                const int token = tok0 + waveM + mi * 16 + q * 4 + r;
                logits[(size_t)token * NEXP + e] =
                    (accH[mi][ni][r] + accC[mi][ni][r] * (1.f / 4096.f)) * (1.f / 64.f);
            }
        }
}

// ================== Kernel 2: softmax + biased top-12, 1 token/wave ==================
// Per-token math bit-identical to round 1/3; only the token->wave mapping changed.

__launch_bounds__(256, 1)
__global__ void topk_kernel(const float* __restrict__ logits,
                            const float* __restrict__ bias,
                            float* __restrict__ out)
{
    const int lane = threadIdx.x & 63;
    const int wave = threadIdx.x >> 6;
    const int tok  = blockIdx.x * 4 + wave;

    const float4 bs0 = *(const float4*)&bias[4 * lane];
    const float4 bs1 = *(const float4*)&bias[256 + 4 * lane];
    const float br[8] = {bs0.x, bs0.y, bs0.z, bs0.w, bs1.x, bs1.y, bs1.z, bs1.w};

    const float4 z0 = *(const float4*)&logits[(size_t)tok * NEXP + 4 * lane];
    const float4 z1 = *(const float4*)&logits[(size_t)tok * NEXP + 256 + 4 * lane];
    float z[8] = {z0.x, z0.y, z0.z, z0.w, z1.x, z1.y, z1.z, z1.w};

    float m = z[0];
    #pragma unroll
    for (int j = 1; j < 8; j++) m = fmaxf(m, z[j]);
    #pragma unroll
    for (int off = 32; off >= 1; off >>= 1) m = fmaxf(m, __shfl_xor(m, off));

    float p[8];
    float s = 0.f;
    #pragma unroll
    for (int j = 0; j < 8; j++) { p[j] = expf(z[j] - m); s += p[j]; }
    #pragma unroll
    for (int off = 32; off >= 1; off >>= 1) s += __shfl_xor(s, off);
    const float inv = 1.f / s;

    float pb[8], bb[8];
    #pragma unroll
    for (int j = 0; j < 8; j++) {
        pb[j] = p[j] * inv;
        bb[j] = pb[j] + br[j];
    }

    for (int kk = 0; kk < TOPK; kk++) {
        unsigned long long key = 0ull;
        #pragma unroll
        for (int j = 0; j < 8; j++) {
            int e = (j < 4) ? (4 * lane + j) : (256 + 4 * lane + (j - 4));
            unsigned long long k64 =
                ((unsigned long long)fkey(bb[j]) << 32) |
                (unsigned long long)(unsigned int)(1023 - e);
            key = (k64 > key) ? k64 : key;
        }
        #pragma unroll
        for (int off = 32; off >= 1; off >>= 1) {
            unsigned long long o = __shfl_xor(key, off);
            key = (o > key) ? o : key;
        }
        const int estar = 1023 - (int)(unsigned int)(key & 0xffffffffull);

        int lstar, jstar;
        if (estar < 256) { lstar = estar >> 2;         jstar = estar & 3; }
        else             { lstar = (estar - 256) >> 2; jstar = 4 + ((estar - 256) & 3); }

        const float pj   = pick8(pb, jstar);
        const float psel = __shfl(pj, lstar);

        if (lane == lstar) {
            if (jstar == 0) bb[0] = -INFINITY;
            if (jstar == 1) bb[1] = -INFINITY;
            if (jstar == 2) bb[2] = -INFINITY;
            if (jstar == 3) bb[3] = -INFINITY;
            if (jstar == 4) bb[4] = -INFINITY;
            if (jstar == 5) bb[5] = -INFINITY;
            if (jstar == 6) bb[6] = -INFINITY;
            if (jstar == 7) bb[7] = -INFINITY;
        }

        if (lane == 0) {
            out[(size_t)tok * TOPK + kk] = psel * RSCALE;
            out[(size_t)T_TOKENS * TOPK + (size_t)tok * TOPK + kk] = (float)estar;
        }
    }
}

// ================== Fallback: round-1 fused fp32 kernel (verified) ==================

#define TM   32
#define BK   16
#define EPAD (NEXP + 4)
#define XPAD 36

__launch_bounds__(256, 1)
__global__ void router_kernel(const float* __restrict__ X,
                              const float* __restrict__ W,
                              const float* __restrict__ bias,
                              float* __restrict__ out)
{
    __shared__ float Wsh[BK][EPAD];
    __shared__ float Xsh[BK][XPAD];

    const int tid  = threadIdx.x;
    const int lane = tid & 63;
    const int wave = tid >> 6;
    const int tok0 = blockIdx.x * TM;

    float acc[8][8];
    #pragma unroll
    for (int i = 0; i < 8; i++)
        #pragma unroll
        for (int j = 0; j < 8; j++) acc[i][j] = 0.f;

    const int xt = tid >> 4;
    const int xk = tid & 15;

    for (int k0 = 0; k0 < HID; k0 += BK) {
        #pragma unroll
        for (int r = 0; r < 2; r++) {
            int t = r * 16 + xt;
            Xsh[xk][t] = X[(size_t)(tok0 + t) * HID + k0 + xk];
        }
        #pragma unroll
        for (int r = 0; r < 8; r++) {
            int flat4 = r * 256 + tid;
            int e  = flat4 >> 2;
            int kq = (flat4 & 3) * 4;
            const float4 wv = *(const float4*)&W[(size_t)e * HID + k0 + kq];
            Wsh[kq + 0][e] = wv.x;
            Wsh[kq + 1][e] = wv.y;
            Wsh[kq + 2][e] = wv.z;
            Wsh[kq + 3][e] = wv.w;
        }
        __syncthreads();

        #pragma unroll
        for (int k = 0; k < BK; k++) {
            float4 b0 = *(const float4*)&Wsh[k][4 * lane];
            float4 b1 = *(const float4*)&Wsh[k][256 + 4 * lane];
            float4 a0 = *(const float4*)&Xsh[k][wave * 8];
            float4 a1 = *(const float4*)&Xsh[k][wave * 8 + 4];
            float a[8] = {a0.x, a0.y, a0.z, a0.w, a1.x, a1.y, a1.z, a1.w};
            float b[8] = {b0.x, b0.y, b0.z, b0.w, b1.x, b1.y, b1.z, b1.w};
            #pragma unroll
            for (int i = 0; i < 8; i++)
                #pragma unroll
                for (int j = 0; j < 8; j++)
                    acc[i][j] = fmaf(a[i], b[j], acc[i][j]);
        }
        __syncthreads();
    }

    const float4 bs0 = *(const float4*)&bias[4 * lane];
    const float4 bs1 = *(const float4*)&bias[256 + 4 * lane];
    const float br[8] = {bs0.x, bs0.y, bs0.z, bs0.w, bs1.x, bs1.y, bs1.z, bs1.w};

    for (int i = 0; i < 8; i++) {
        const int tok = tok0 + wave * 8 + i;

        float m = acc[i][0];
        #pragma unroll
        for (int j = 1; j < 8; j++) m = fmaxf(m, acc[i][j]);
        #pragma unroll
        for (int off = 32; off >= 1; off >>= 1) m = fmaxf(m, __shfl_xor(m, off));

        float p[8];
        float s = 0.f;
        #pragma unroll
        for (int j = 0; j < 8; j++) { p[j] = expf(acc[i][j] - m); s += p[j]; }
        #pragma unroll
        for (int off = 32; off >= 1; off >>= 1) s += __shfl_xor(s, off);
        const float inv = 1.f / s;

        float pb[8], bb[8];
        #pragma unroll
        for (int j = 0; j < 8; j++) {
            pb[j] = p[j] * inv;
            bb[j] = pb[j] + br[j];
        }

        for (int kk = 0; kk < TOPK; kk++) {
            unsigned long long key = 0ull;
            #pragma unroll
            for (int j = 0; j < 8; j++) {
                int e = (j < 4) ? (4 * lane + j) : (256 + 4 * lane + (j - 4));
                unsigned long long k64 =
                    ((unsigned long long)fkey(bb[j]) << 32) |
                    (unsigned long long)(unsigned int)(1023 - e);
                key = (k64 > key) ? k64 : key;
            }
            #pragma unroll
            for (int off = 32; off >= 1; off >>= 1) {
                unsigned long long o = __shfl_xor(key, off);
                key = (o > key) ? o : key;
            }
            const int estar = 1023 - (int)(unsigned int)(key & 0xffffffffull);

            int lstar, jstar;
            if (estar < 256) { lstar = estar >> 2;         jstar = estar & 3; }
            else             { lstar = (estar - 256) >> 2; jstar = 4 + ((estar - 256) & 3); }

            const float pj   = pick8(pb, jstar);
            const float psel = __shfl(pj, lstar);

            if (lane == lstar) {
                if (jstar == 0) bb[0] = -INFINITY;
                if (jstar == 1) bb[1] = -INFINITY;
                if (jstar == 2) bb[2] = -INFINITY;
                if (jstar == 3) bb[3] = -INFINITY;
                if (jstar == 4) bb[4] = -INFINITY;
                if (jstar == 5) bb[5] = -INFINITY;
                if (jstar == 6) bb[6] = -INFINITY;
                if (jstar == 7) bb[7] = -INFINITY;
            }

            if (lane == 0) {
                out[(size_t)tok * TOPK + kk] = psel * RSCALE;
                out[(size_t)T_TOKENS * TOPK + (size_t)tok * TOPK + kk] = (float)estar;
            }
        }
    }
}

// ================== launcher ==================

extern "C" void kernel_launch(void* const* d_in, const int* in_sizes, int n_in,
                              void* d_out, int out_size, void* d_ws, size_t ws_size,
                              hipStream_t stream)
{
    const float* X    = (const float*)d_in[0];   // [8192, 4096]
    const float* W    = (const float*)d_in[1];   // [512, 4096]
    const float* bias = (const float*)d_in[2];   // [512]
    float* out = (float*)d_out;

    const size_t logits_bytes = (size_t)T_TOKENS * NEXP * sizeof(float);   // 16 MB
    const size_t wp_bytes     = (size_t)NEXP * HID * 4;                    // 8 MB (2 fp16 planes)

    if (ws_size >= logits_bytes + wp_bytes) {
        float* logits = (float*)d_ws;
        uint4* Wp     = (uint4*)((char*)d_ws + logits_bytes);
        wconv_kernel<<<dim3(2048), dim3(256), 0, stream>>>(W, Wp);
        gemm2_kernel<<<dim3(256), dim3(256), 0, stream>>>(X, Wp, logits);
        topk_kernel<<<dim3(T_TOKENS / 4), dim3(256), 0, stream>>>(logits, bias, out);
    } else if (ws_size >= logits_bytes) {
        float* logits = (float*)d_ws;
        gemm_kernel<<<dim3(256), dim3(256), 0, stream>>>(X, W, logits);
        topk_kernel<<<dim3(T_TOKENS / 4), dim3(256), 0, stream>>>(logits, bias, out);
    } else {
        router_kernel<<<dim3(T_TOKENS / TM), dim3(256), 0, stream>>>(X, W, bias, out);
    }
}